// Round 7
// baseline (198.113 us; speedup 1.0000x reference)
//
#include <hip/hip_runtime.h>
#include <math.h>

// NEAT forward, round 7: single fused kernel (prep + grid barrier + fwd).
//  - prep: one wave sorts one neuron's 64 edges (lane=edge) via ballot.
//    WINDOW-ANCHORED schedule: slot = 4c + rank for rank<4 (fixed windows,
//    no cumulative-histogram drift like R5/R6); spill edges (rank>=4)
//    bijectively matched to holes via a second ballot pass. With the
//    sigma rotation (bijection on 0..63), non-spill edges give exactly
//    4 lanes per bank-pair per time-slot (the b64 floor).
//  - grid barrier: threadfence + device atomicAdd + acquire spin.
//    256 blocks x 1024 thr, LDS 75.8KB -> HW capacity 2 blocks/CU,
//    so all 256 blocks are co-resident (no deadlock). flag zeroed
//    per-call via hipMemsetAsync (graph-capture-safe).
//  - fwd: identical to R6 (f16 act in LDS, 16-record reg prefetch,
//    fma_mix inner loop, f32 output).

#define N_IN    512
#define NLAYER  9
#define DEG     64
#define BATCH   1024
#define BPB     4
#define THREADS 1024
#define TOTAL_N 8960            // 512 + 8*1024 + 256
#define N_OUT   256
#define NEDGE_N 8448            // edge-owning neurons
#define GRID    256
#define PREPW   (GRID * 16)     // prep waves

union H4 { uint2 u; _Float16 h[4]; };
union H2 { unsigned u; _Float16 h[2]; };
union HS { _Float16 h; unsigned short s; };

__global__ __launch_bounds__(THREADS, 4)
void neat_fused(const float* __restrict__ in,
                const float* __restrict__ wts,
                const int*   __restrict__ sidx,
                uint4*       __restrict__ rec,
                int*         __restrict__ flag,
                float*       __restrict__ out)
{
    __shared__ _Float16 act[TOTAL_N * BPB];   // 71,680 B
    __shared__ unsigned sortbuf[16][64];      //  4,096 B

    const int tid   = threadIdx.x;
    const int wave  = tid >> 6;
    const int lane  = tid & 63;
    const int bbase = blockIdx.x * BPB;

    // ---- stage inputs (f32 -> f16) ----
    {
        const float* src = in + bbase * N_IN;
        for (int t = tid; t < BPB * N_IN; t += THREADS) {
            int j = t >> 9;
            int i = t & (N_IN - 1);
            act[i * BPB + j] = (_Float16)src[t];
        }
    }

    // ---- prep: one wave sorts one neuron per iteration ----
    const unsigned long long lt = (1ull << lane) - 1ull;
    const int wgid = blockIdx.x * 16 + wave;
    for (int t = wgid; t < NEDGE_N; t += PREPW) {   // trip count uniform per block
        const int e   = (t << 6) + lane;            // coalesced
        const int idx = sidx[e];
        HS w; w.h = (_Float16)wts[e];
        const int c = idx & 15;                     // bank-pair class

        // pass 1: rank within class, spill ordinal prefix
        int rank = 0, spillbefore = 0;
        #pragma unroll
        for (int cc = 0; cc < 16; ++cc) {
            const unsigned long long m = __ballot(c == cc);
            const int n = (int)__popcll(m);
            if (cc == c) rank = (int)__popcll(m & lt);
            spillbefore += (cc < c && n > 4) ? (n - 4) : 0;
        }
        const bool spill = (rank >= 4);
        int slot_pre = spill ? -1 : ((c << 2) + rank);
        const int myspill = spillbefore + rank - 4;   // valid when spill

        // pass 2: match spill #myspill to hole #myspill
        int hcum = 0;
        #pragma unroll
        for (int cc = 0; cc < 16; ++cc) {
            const unsigned long long m = __ballot(c == cc);
            const int n = (int)__popcll(m);
            int holes = 4 - n; holes = holes > 0 ? holes : 0;
            const bool take = (slot_pre < 0) && (myspill < hcum + holes);
            slot_pre = take ? ((cc << 2) + n + (myspill - hcum)) : slot_pre;
            hcum += holes;
        }

        const int fl    = t & 63;                   // fwd lane of this neuron
        const int sigma = ((fl & 15) << 2) | (fl >> 4);   // bijection 0..63
        const int slot  = (slot_pre + sigma) & 63;
        sortbuf[wave][slot] = (unsigned)idx | ((unsigned)w.s << 16);
        __syncthreads();
        if (lane < 16) {                            // pack 4 slots -> 1 record
            const unsigned s0 = sortbuf[wave][(lane << 2) + 0];
            const unsigned s1 = sortbuf[wave][(lane << 2) + 1];
            const unsigned s2 = sortbuf[wave][(lane << 2) + 2];
            const unsigned s3 = sortbuf[wave][(lane << 2) + 3];
            uint4 o;
            o.x = (s0 & 0xffffu) | (s1 << 16);
            o.y = (s2 & 0xffffu) | (s3 << 16);
            o.z = (s0 >> 16) | (s1 & 0xffff0000u);
            o.w = (s2 >> 16) | (s3 & 0xffff0000u);
            rec[((t >> 6) << 10) + (lane << 6) + fl] = o;
        }
        __syncthreads();
    }

    // ---- grid barrier ----
    __threadfence();
    __syncthreads();
    if (tid == 0) {
        atomicAdd(flag, 1);                         // device-scope
        while (__hip_atomic_load(flag, __ATOMIC_ACQUIRE,
                                 __HIP_MEMORY_SCOPE_AGENT) < GRID) {
            __builtin_amdgcn_s_sleep(2);
        }
    }
    __syncthreads();
    __threadfence();

    // ---- fwd: 9 layers ----
    int recBase = 0;
    int nb      = N_IN;
    #pragma unroll 1
    for (int layer = 0; layer < NLAYER; ++layer) {
        const int n = (layer < NLAYER - 1) ? 1024 : N_OUT;
        if (tid < n) {
            const int neuron = tid;
            const uint4* rp = rec + recBase + ((neuron >> 6) << 10) + (neuron & 63);

            uint4 r[16];
            #pragma unroll
            for (int q = 0; q < 16; ++q) r[q] = rp[q << 6];

            float4 acc = make_float4(0.f, 0.f, 0.f, 0.f);
            #pragma unroll
            for (int q = 0; q < 16; ++q) {
                const uint4 r4 = r[q];
                H4 g0, g1, g2, g3;
                g0.u = *reinterpret_cast<const uint2*>(act + ((r4.x & 0xffffu) << 2));
                g1.u = *reinterpret_cast<const uint2*>(act + ((r4.x >> 16) << 2));
                g2.u = *reinterpret_cast<const uint2*>(act + ((r4.y & 0xffffu) << 2));
                g3.u = *reinterpret_cast<const uint2*>(act + ((r4.y >> 16) << 2));
                H2 wz, ww; wz.u = r4.z; ww.u = r4.w;
                acc.x += (float)g0.h[0] * (float)wz.h[0];
                acc.y += (float)g0.h[1] * (float)wz.h[0];
                acc.z += (float)g0.h[2] * (float)wz.h[0];
                acc.w += (float)g0.h[3] * (float)wz.h[0];
                acc.x += (float)g1.h[0] * (float)wz.h[1];
                acc.y += (float)g1.h[1] * (float)wz.h[1];
                acc.z += (float)g1.h[2] * (float)wz.h[1];
                acc.w += (float)g1.h[3] * (float)wz.h[1];
                acc.x += (float)g2.h[0] * (float)ww.h[0];
                acc.y += (float)g2.h[1] * (float)ww.h[0];
                acc.z += (float)g2.h[2] * (float)ww.h[0];
                acc.w += (float)g2.h[3] * (float)ww.h[0];
                acc.x += (float)g3.h[0] * (float)ww.h[1];
                acc.y += (float)g3.h[1] * (float)ww.h[1];
                acc.z += (float)g3.h[2] * (float)ww.h[1];
                acc.w += (float)g3.h[3] * (float)ww.h[1];
            }

            float4 sg;
            sg.x = 1.f / (1.f + __expf(-acc.x));
            sg.y = 1.f / (1.f + __expf(-acc.y));
            sg.z = 1.f / (1.f + __expf(-acc.z));
            sg.w = 1.f / (1.f + __expf(-acc.w));

            if (layer < NLAYER - 1) {
                H4 p;
                p.h[0] = (_Float16)sg.x; p.h[1] = (_Float16)sg.y;
                p.h[2] = (_Float16)sg.z; p.h[3] = (_Float16)sg.w;
                *reinterpret_cast<uint2*>(act + ((nb + neuron) << 2)) = p.u;
            } else {
                float* op = out + neuron;           // f32 output
                op[(bbase + 0) * N_OUT] = sg.x;
                op[(bbase + 1) * N_OUT] = sg.y;
                op[(bbase + 2) * N_OUT] = sg.z;
                op[(bbase + 3) * N_OUT] = sg.w;
            }
        }
        __syncthreads();
        recBase += n << 4;
        nb      += n;
    }
}

extern "C" void kernel_launch(void* const* d_in, const int* in_sizes, int n_in,
                              void* d_out, int out_size, void* d_ws, size_t ws_size,
                              hipStream_t stream)
{
    const float* in  = (const float*)d_in[0];
    const float* wts = (const float*)d_in[1];
    const int*   sx  = (const int*)d_in[2];
    float*       out = (float*)d_out;

    int*   flag = (int*)d_ws;
    uint4* rec  = (uint4*)((char*)d_ws + 256);   // 256 + 2,162,688 B used

    hipMemsetAsync(d_ws, 0, 256, stream);        // zero barrier flag each call
    neat_fused<<<GRID, THREADS, 0, stream>>>(in, wts, sx, rec, flag, out);
}

// Round 8
// 49.424 us; speedup vs baseline: 4.0085x; 4.0085x over previous
//
#include <hip/hip_runtime.h>
#include <math.h>

// NEAT forward, round 8: two kernels again (R7 fusion regressed 4x).
//  - prep: WIDE launch — one wave per neuron (8448 waves, 2112 blocks),
//    window-anchored ballot sort from R7 (slot = 4c+rank, spills matched
//    to holes; verified conflict cycles 9.3e6 -> 7.6e6). R6's prep was
//    only 132 blocks = zero latency hiding; width fixes that.
//  - fwd: unchanged from R6 (f16 act LDS, 16-record reg prefetch,
//    fma_mix inner loop, f32 out).

#define N_IN    512
#define NLAYER  9
#define DEG     64
#define BATCH   1024
#define BPB     4
#define THREADS 1024
#define TOTAL_N 8960            // 512 + 8*1024 + 256
#define N_OUT   256
#define NEDGE_N 8448            // edge-owning neurons

union H4 { uint2 u; _Float16 h[4]; };
union H2 { unsigned u; _Float16 h[2]; };
union HS { _Float16 h; unsigned short s; };

// ---- prep: one wave per neuron, window-anchored ballot sort ----
__global__ __launch_bounds__(256)
void neat_prep(const float* __restrict__ wts,
               const int*   __restrict__ sidx,
               uint4*       __restrict__ rec)
{
    __shared__ unsigned sortbuf[4][64];   // 1 KB, one row per wave

    const int tid  = threadIdx.x;
    const int wave = tid >> 6;
    const int lane = tid & 63;
    const int t    = blockIdx.x * 4 + wave;          // neuron 0..8447
    const unsigned long long lt = (1ull << lane) - 1ull;

    const int e   = (t << 6) + lane;                 // coalesced
    const int idx = sidx[e];
    HS w; w.h = (_Float16)wts[e];
    const int c = idx & 15;                          // bank-pair class

    // pass 1: rank within class, spill ordinal prefix
    int rank = 0, spillbefore = 0;
    #pragma unroll
    for (int cc = 0; cc < 16; ++cc) {
        const unsigned long long m = __ballot(c == cc);
        const int n = (int)__popcll(m);
        if (cc == c) rank = (int)__popcll(m & lt);
        spillbefore += (cc < c && n > 4) ? (n - 4) : 0;
    }
    const bool spill = (rank >= 4);
    int slot_pre = spill ? -1 : ((c << 2) + rank);
    const int myspill = spillbefore + rank - 4;      // valid when spill

    // pass 2: match spill #myspill to hole #myspill
    int hcum = 0;
    #pragma unroll
    for (int cc = 0; cc < 16; ++cc) {
        const unsigned long long m = __ballot(c == cc);
        const int n = (int)__popcll(m);
        int holes = 4 - n; holes = holes > 0 ? holes : 0;
        const bool take = (slot_pre < 0) && (myspill < hcum + holes);
        slot_pre = take ? ((cc << 2) + n + (myspill - hcum)) : slot_pre;
        hcum += holes;
    }

    const int fl    = t & 63;                        // fwd lane of this neuron
    const int sigma = ((fl & 15) << 2) | (fl >> 4);  // bijection on 0..63
    const int slot  = (slot_pre + sigma) & 63;
    sortbuf[wave][slot] = (unsigned)idx | ((unsigned)w.s << 16);
    __syncthreads();

    if (lane < 16) {                                 // pack 4 slots -> 1 record
        const unsigned s0 = sortbuf[wave][(lane << 2) + 0];
        const unsigned s1 = sortbuf[wave][(lane << 2) + 1];
        const unsigned s2 = sortbuf[wave][(lane << 2) + 2];
        const unsigned s3 = sortbuf[wave][(lane << 2) + 3];
        uint4 o;
        o.x = (s0 & 0xffffu) | (s1 << 16);
        o.y = (s2 & 0xffffu) | (s3 << 16);
        o.z = (s0 >> 16) | (s1 & 0xffff0000u);
        o.w = (s2 >> 16) | (s3 & 0xffff0000u);
        rec[((t >> 6) << 10) + (lane << 6) + fl] = o;
    }
}

__global__ __launch_bounds__(THREADS, 4)
void neat_fwd(const float* __restrict__ in,
              const uint4* __restrict__ rec,
              float*       __restrict__ out)
{
    __shared__ _Float16 act[TOTAL_N * BPB];          // 71,680 B

    const int tid   = threadIdx.x;
    const int bbase = blockIdx.x * BPB;

    // ---- stage inputs (f32 -> f16) ----
    {
        const float* src = in + bbase * N_IN;
        for (int t = tid; t < BPB * N_IN; t += THREADS) {
            int j = t >> 9;
            int i = t & (N_IN - 1);
            act[i * BPB + j] = (_Float16)src[t];
        }
    }
    __syncthreads();

    int recBase = 0;
    int nb      = N_IN;
    #pragma unroll 1
    for (int layer = 0; layer < NLAYER; ++layer) {
        const int n = (layer < NLAYER - 1) ? 1024 : N_OUT;
        if (tid < n) {
            const int neuron = tid;
            const uint4* rp = rec + recBase + ((neuron >> 6) << 10) + (neuron & 63);

            uint4 r[16];
            #pragma unroll
            for (int q = 0; q < 16; ++q) r[q] = rp[q << 6];

            float4 acc = make_float4(0.f, 0.f, 0.f, 0.f);
            #pragma unroll
            for (int q = 0; q < 16; ++q) {
                const uint4 r4 = r[q];
                H4 g0, g1, g2, g3;
                g0.u = *reinterpret_cast<const uint2*>(act + ((r4.x & 0xffffu) << 2));
                g1.u = *reinterpret_cast<const uint2*>(act + ((r4.x >> 16) << 2));
                g2.u = *reinterpret_cast<const uint2*>(act + ((r4.y & 0xffffu) << 2));
                g3.u = *reinterpret_cast<const uint2*>(act + ((r4.y >> 16) << 2));
                H2 wz, ww; wz.u = r4.z; ww.u = r4.w;
                acc.x += (float)g0.h[0] * (float)wz.h[0];
                acc.y += (float)g0.h[1] * (float)wz.h[0];
                acc.z += (float)g0.h[2] * (float)wz.h[0];
                acc.w += (float)g0.h[3] * (float)wz.h[0];
                acc.x += (float)g1.h[0] * (float)wz.h[1];
                acc.y += (float)g1.h[1] * (float)wz.h[1];
                acc.z += (float)g1.h[2] * (float)wz.h[1];
                acc.w += (float)g1.h[3] * (float)wz.h[1];
                acc.x += (float)g2.h[0] * (float)ww.h[0];
                acc.y += (float)g2.h[1] * (float)ww.h[0];
                acc.z += (float)g2.h[2] * (float)ww.h[0];
                acc.w += (float)g2.h[3] * (float)ww.h[0];
                acc.x += (float)g3.h[0] * (float)ww.h[1];
                acc.y += (float)g3.h[1] * (float)ww.h[1];
                acc.z += (float)g3.h[2] * (float)ww.h[1];
                acc.w += (float)g3.h[3] * (float)ww.h[1];
            }

            float4 sg;
            sg.x = 1.f / (1.f + __expf(-acc.x));
            sg.y = 1.f / (1.f + __expf(-acc.y));
            sg.z = 1.f / (1.f + __expf(-acc.z));
            sg.w = 1.f / (1.f + __expf(-acc.w));

            if (layer < NLAYER - 1) {
                H4 p;
                p.h[0] = (_Float16)sg.x; p.h[1] = (_Float16)sg.y;
                p.h[2] = (_Float16)sg.z; p.h[3] = (_Float16)sg.w;
                *reinterpret_cast<uint2*>(act + ((nb + neuron) << 2)) = p.u;
            } else {
                float* op = out + neuron;            // f32 output
                op[(bbase + 0) * N_OUT] = sg.x;
                op[(bbase + 1) * N_OUT] = sg.y;
                op[(bbase + 2) * N_OUT] = sg.z;
                op[(bbase + 3) * N_OUT] = sg.w;
            }
        }
        __syncthreads();
        recBase += n << 4;
        nb      += n;
    }
}

extern "C" void kernel_launch(void* const* d_in, const int* in_sizes, int n_in,
                              void* d_out, int out_size, void* d_ws, size_t ws_size,
                              hipStream_t stream)
{
    const float* in  = (const float*)d_in[0];
    const float* wts = (const float*)d_in[1];
    const int*   sx  = (const int*)d_in[2];
    float*       out = (float*)d_out;
    uint4*       rec = (uint4*)d_ws;    // 135,168 * 16 = 2,162,688 B

    neat_prep<<<NEDGE_N / 4, 256, 0, stream>>>(wts, sx, rec);
    neat_fwd<<<BATCH / BPB, THREADS, 0, stream>>>(in, rec, out);
}